// Round 4
// baseline (2246.297 us; speedup 1.0000x reference)
//
#include <hip/hip_runtime.h>

// StimulusModel: per-element 256-step recurrence, FLOAT32 in/out.
//   g      = 2 * sigmoid(u - u_trigger)           (BETA=1, G_MAX=2)
//   u_next = clip(u + 0.05 - 0.1*g, 0.01, 0.2)
// Outputs concatenated: u_hist[steps][B] ++ g_hist[steps][B], f32 = 2.15 GB stores.
//
// R3 post-mortem: rocprof top-5 (sorted by dur_us) excludes this kernel while
// fills show 1400us @ 6.15 TB/s -> kernel itself is <1410us; bench dur_us
// (~2190) includes harness poison fills (~1750us floor). Kernel est. ~435us vs
// 350us write floor. This round: nt stores + 2x waves (VEC=2) to close the gap.

#define VEC 2      // f32 elements per thread -> float2 stores, 8 waves/SIMD
#define UNROLL 8   // time steps buffered per store burst (steps=256 divisible)

typedef float v2f __attribute__((ext_vector_type(2)));

__global__ __launch_bounds__(256) void stimulus_kernel(
    const float* __restrict__ u_init,   // [B] f32
    const float* __restrict__ ut_p,     // [1] f32
    float* __restrict__ u_hist,         // [steps][B] f32
    float* __restrict__ g_hist,         // [steps][B] f32
    int B, int steps)
{
    const int tid = blockIdx.x * blockDim.x + threadIdx.x;
    const size_t base = (size_t)tid * VEC;
    if (base >= (size_t)B) return;

    const float ut = ut_p[0];

    v2f in = *(const v2f*)(u_init + base);
    float u[VEC] = {in.x, in.y};

    float* up = u_hist + base;
    float* gp = g_hist + base;

    v2f ubuf[UNROLL], gbuf[UNROLL];

    for (int t0 = 0; t0 < steps; t0 += UNROLL) {
        // compute phase: UNROLL steps into distinct registers
        #pragma unroll
        for (int s = 0; s < UNROLL; ++s) {
            float g[VEC];
            #pragma unroll
            for (int j = 0; j < VEC; ++j) {
                // g = 2*sigmoid(u - ut) = 2 / (1 + exp(ut - u))
                float e = __expf(ut - u[j]);
                float gg = 2.0f * __builtin_amdgcn_rcpf(1.0f + e);  // v_rcp_f32
                float un = u[j] + (0.05f - 0.1f * gg);
                un = fminf(fmaxf(un, 0.01f), 0.2f);   // clip [U_MIN, U_MAX]
                u[j] = un;
                g[j] = gg;
            }
            ubuf[s].x = u[0]; ubuf[s].y = u[1];
            gbuf[s].x = g[0]; gbuf[s].y = g[1];
        }
        // burst phase: 16 independent non-temporal dwordx2 stores
        #pragma unroll
        for (int s = 0; s < UNROLL; ++s) {
            __builtin_nontemporal_store(ubuf[s], (v2f*)up);
            __builtin_nontemporal_store(gbuf[s], (v2f*)gp);
            up += B;
            gp += B;
        }
    }
}

extern "C" void kernel_launch(void* const* d_in, const int* in_sizes, int n_in,
                              void* d_out, int out_size, void* d_ws, size_t ws_size,
                              hipStream_t stream) {
    const float* u_init = (const float*)d_in[0];
    const float* ut     = (const float*)d_in[1];
    const int B = in_sizes[0];
    const int steps = out_size / (2 * B);   // out = u_hist ++ g_hist

    float* u_hist = (float*)d_out;
    float* g_hist = u_hist + (size_t)steps * (size_t)B;

    const int threads = (B + VEC - 1) / VEC;
    const int block = 256;
    const int grid = (threads + block - 1) / block;
    hipLaunchKernelGGL(stimulus_kernel, dim3(grid), dim3(block), 0, stream,
                       u_init, ut, u_hist, g_hist, B, steps);
}

// Round 6
// 2216.792 us; speedup vs baseline: 1.0133x; 1.0133x over previous
//
#include <hip/hip_runtime.h>

// StimulusModel: per-element 256-step recurrence, FLOAT32 in/out.
//   g      = 2 * sigmoid(u - u_trigger)           (BETA=1, G_MAX=2)
//   u_next = clip(u + 0.05 - 0.1*g, 0.01, 0.2)
// Outputs concatenated: u_hist[steps][B] ++ g_hist[steps][B], f32 = 2.15 GB stores.
//
// R5 was a compile failure: __builtin_nontemporal_store requires a real vector
// type, not HIP_vector_type<float,4>. Same experiment, ext_vector_type fix:
// R3 config (16B stores, 8-step burst) + nt stores only.
// Timed total = ~1740us harness poison fills (fixed) + kernel (~450us, floor 350).

#define VEC 4      // f32 elements per thread -> dwordx4 stores
#define UNROLL 8   // time steps buffered per store burst (steps=256 divisible)

typedef float v4f __attribute__((ext_vector_type(4)));

__global__ __launch_bounds__(256) void stimulus_kernel(
    const float* __restrict__ u_init,   // [B] f32
    const float* __restrict__ ut_p,     // [1] f32
    float* __restrict__ u_hist,         // [steps][B] f32
    float* __restrict__ g_hist,         // [steps][B] f32
    int B, int steps)
{
    const int tid = blockIdx.x * blockDim.x + threadIdx.x;
    const size_t base = (size_t)tid * VEC;
    if (base >= (size_t)B) return;

    const float ut = ut_p[0];

    v4f in = *(const v4f*)(u_init + base);
    float u[VEC] = {in.x, in.y, in.z, in.w};

    float* up = u_hist + base;
    float* gp = g_hist + base;

    v4f ubuf[UNROLL], gbuf[UNROLL];

    for (int t0 = 0; t0 < steps; t0 += UNROLL) {
        // compute phase: UNROLL steps into distinct registers
        #pragma unroll
        for (int s = 0; s < UNROLL; ++s) {
            float g[VEC];
            #pragma unroll
            for (int j = 0; j < VEC; ++j) {
                // g = 2*sigmoid(u - ut) = 2 / (1 + exp(ut - u))
                float e = __expf(ut - u[j]);
                float gg = 2.0f * __builtin_amdgcn_rcpf(1.0f + e);  // v_rcp_f32
                float un = u[j] + (0.05f - 0.1f * gg);
                un = fminf(fmaxf(un, 0.01f), 0.2f);   // clip [U_MIN, U_MAX]
                u[j] = un;
                g[j] = gg;
            }
            v4f uv = {u[0], u[1], u[2], u[3]};
            v4f gv = {g[0], g[1], g[2], g[3]};
            ubuf[s] = uv;
            gbuf[s] = gv;
        }
        // burst phase: 16 independent non-temporal dwordx4 stores
        #pragma unroll
        for (int s = 0; s < UNROLL; ++s) {
            __builtin_nontemporal_store(ubuf[s], (v4f*)up);
            __builtin_nontemporal_store(gbuf[s], (v4f*)gp);
            up += B;
            gp += B;
        }
    }
}

extern "C" void kernel_launch(void* const* d_in, const int* in_sizes, int n_in,
                              void* d_out, int out_size, void* d_ws, size_t ws_size,
                              hipStream_t stream) {
    const float* u_init = (const float*)d_in[0];
    const float* ut     = (const float*)d_in[1];
    const int B = in_sizes[0];
    const int steps = out_size / (2 * B);   // out = u_hist ++ g_hist

    float* u_hist = (float*)d_out;
    float* g_hist = u_hist + (size_t)steps * (size_t)B;

    const int threads = (B + VEC - 1) / VEC;
    const int block = 256;
    const int grid = (threads + block - 1) / block;
    hipLaunchKernelGGL(stimulus_kernel, dim3(grid), dim3(block), 0, stream,
                       u_init, ut, u_hist, g_hist, B, steps);
}

// Round 7
// 2195.316 us; speedup vs baseline: 1.0232x; 1.0098x over previous
//
#include <hip/hip_runtime.h>

// StimulusModel: per-element 256-step recurrence, FLOAT32 in/out.
//   g      = 2 * sigmoid(u - u_trigger)           (BETA=1, G_MAX=2)
//   u_next = clip(u + 0.05 - 0.1*g, 0.01, 0.2)
// Outputs concatenated: u_hist[steps][B] ++ g_hist[steps][B], f32 = 2.15 GB stores.
//
// Ledger: fixed harness poison fills ~1740us/iter; kernel ~450us vs 350us floor.
// Falsified: store-burst depth (R3), 8B stores (R4, -2.3%), nt stores (R6, -1.3%,
// plus pathological 8x RMW fetch on cold dispatch). This round: time-split x2 —
// 2048 blocks, each chunk covered by two blocks (t<128 / t>=128 with 128
// register-only warm-up steps, bit-exact, ~5us). Doubles waves/SIMD (4->8) and
// halves each wave's 4MB-stride row walk (store-parallelism / TLB mechanism).

#define VEC 4      // f32 elements per thread -> dwordx4 stores
#define TSPLIT 2   // time-halves per element chunk

__global__ __launch_bounds__(256) void stimulus_kernel(
    const float* __restrict__ u_init,   // [B] f32
    const float* __restrict__ ut_p,     // [1] f32
    float* __restrict__ u_hist,         // [steps][B] f32
    float* __restrict__ g_hist,         // [steps][B] f32
    int B, int steps)
{
    const int half = blockIdx.x & (TSPLIT - 1);
    const int cb   = blockIdx.x >> 1;            // chunk block
    const int tid  = cb * blockDim.x + threadIdx.x;
    const size_t base = (size_t)tid * VEC;
    if (base >= (size_t)B) return;

    const float ut = ut_p[0];
    const int half_steps = steps / TSPLIT;
    const int t_begin = half * half_steps;
    const int t_end   = t_begin + half_steps;

    float4 in = *(const float4*)(u_init + base);
    float u[VEC] = {in.x, in.y, in.z, in.w};

    // warm-up: advance recurrence to t_begin, register-only (bit-exact replay)
    for (int t = 0; t < t_begin; ++t) {
        #pragma unroll
        for (int j = 0; j < VEC; ++j) {
            float e = __expf(ut - u[j]);
            float gg = 2.0f * __builtin_amdgcn_rcpf(1.0f + e);
            float un = u[j] + (0.05f - 0.1f * gg);
            u[j] = fminf(fmaxf(un, 0.01f), 0.2f);
        }
    }

    float* up = u_hist + (size_t)t_begin * B + base;
    float* gp = g_hist + (size_t)t_begin * B + base;

    for (int t = t_begin; t < t_end; ++t) {
        float g[VEC];
        #pragma unroll
        for (int j = 0; j < VEC; ++j) {
            // g = 2*sigmoid(u - ut) = 2 / (1 + exp(ut - u))
            float e = __expf(ut - u[j]);
            float gg = 2.0f * __builtin_amdgcn_rcpf(1.0f + e);  // v_rcp_f32
            float un = u[j] + (0.05f - 0.1f * gg);
            un = fminf(fmaxf(un, 0.01f), 0.2f);   // clip [U_MIN, U_MAX]
            u[j] = un;
            g[j] = gg;
        }
        *(float4*)up = make_float4(u[0], u[1], u[2], u[3]);
        *(float4*)gp = make_float4(g[0], g[1], g[2], g[3]);
        up += B;
        gp += B;
    }
}

extern "C" void kernel_launch(void* const* d_in, const int* in_sizes, int n_in,
                              void* d_out, int out_size, void* d_ws, size_t ws_size,
                              hipStream_t stream) {
    const float* u_init = (const float*)d_in[0];
    const float* ut     = (const float*)d_in[1];
    const int B = in_sizes[0];
    const int steps = out_size / (2 * B);   // out = u_hist ++ g_hist

    float* u_hist = (float*)d_out;
    float* g_hist = u_hist + (size_t)steps * (size_t)B;

    const int threads = (B + VEC - 1) / VEC;
    const int block = 256;
    const int grid = ((threads + block - 1) / block) * TSPLIT;
    hipLaunchKernelGGL(stimulus_kernel, dim3(grid), dim3(block), 0, stream,
                       u_init, ut, u_hist, g_hist, B, steps);
}